// Round 1
// baseline (4405.368 us; speedup 1.0000x reference)
//
#include <hip/hip_runtime.h>

#define NN 100000

// ---------------------------------------------------------------------------
// Edge index may arrive as int32 (harness doc) or int64 (reference dtype).
// Detect at runtime: for int64 little-endian, every odd 32-bit word is the
// high word of a value < 100000 => zero. For int32, odd words are random
// src values (prob of 2048 consecutive zeros ~ 0).
// ---------------------------------------------------------------------------
__device__ __forceinline__ int eload(const void* e, long i, int is64) {
  if (is64) return (int)((const long long*)e)[i];
  return ((const int*)e)[i];
}

__global__ void k_detect(const unsigned* __restrict__ e, int* __restrict__ flag) {
  if (threadIdx.x == 0 && blockIdx.x == 0) {
    unsigned acc = 0;
    for (int i = 1; i < 4096; i += 2) acc |= e[i];
    *flag = (acc == 0) ? 1 : 0;  // 1 => int64
  }
}

__global__ void k_deg_init(float* __restrict__ deg) {
  int i = blockIdx.x * 256 + threadIdx.x;
  if (i < NN) deg[i] = 1.0f;  // self-loop
}

__global__ void k_deg_accum(const void* __restrict__ e, const int* __restrict__ flag,
                            int E, float* __restrict__ deg) {
  int t = blockIdx.x * 256 + threadIdx.x;
  if (t < E) {
    int d = eload(e, (long)E + t, *flag);
    atomicAdd(&deg[d], 1.0f);
  }
}

__global__ void k_rsqrt(float* __restrict__ deg) {
  int i = blockIdx.x * 256 + threadIdx.x;
  if (i < NN) deg[i] = rsqrtf(deg[i]);  // deg >= 1 always (self-loop)
}

// ---------------------------------------------------------------------------
// Y[N x COUT] = X[N x 128] @ W[128 x COUT], optional relu on X load.
// 256 threads/block, 16 rows/block. W staged in 64-col chunks (32KB LDS),
// X tile 8KB LDS. All loads float4.
// ---------------------------------------------------------------------------
template <int COUT, bool RELU>
__global__ __launch_bounds__(256) void gemm_x_w(const float* __restrict__ X,
                                                const float* __restrict__ W,
                                                float* __restrict__ Y) {
  __shared__ float Wl[128 * 64];
  __shared__ float Xl[16 * 128];
  const int tid = threadIdx.x;
  const long row0 = (long)blockIdx.x * 16;

  // stage X tile: 16 rows x 128 cols = 512 float4
  for (int i = tid; i < 512; i += 256) {
    int r = i >> 5, c4 = (i & 31) << 2;
    float4 v = *(const float4*)&X[(row0 + r) * 128 + c4];
    if (RELU) {
      v.x = fmaxf(v.x, 0.f); v.y = fmaxf(v.y, 0.f);
      v.z = fmaxf(v.z, 0.f); v.w = fmaxf(v.w, 0.f);
    }
    *(float4*)&Xl[r * 128 + c4] = v;
  }

  const int col = tid & 63;
  const int g = tid >> 6;  // 0..3, 4 rows each

  for (int ch = 0; ch < COUT / 64; ++ch) {
    __syncthreads();  // guards X staging (ch=0) and Wl reuse (ch>0)
    // stage W chunk: 128 x 64 (2048 float4)
    for (int i = tid; i < 2048; i += 256) {
      int k = i >> 4, c4 = (i & 15) << 2;
      *(float4*)&Wl[k * 64 + c4] = *(const float4*)&W[(long)k * COUT + ch * 64 + c4];
    }
    __syncthreads();

    float acc[4] = {0.f, 0.f, 0.f, 0.f};
#pragma unroll 4
    for (int k4 = 0; k4 < 128; k4 += 4) {
      float w0 = Wl[(k4 + 0) * 64 + col];
      float w1 = Wl[(k4 + 1) * 64 + col];
      float w2 = Wl[(k4 + 2) * 64 + col];
      float w3 = Wl[(k4 + 3) * 64 + col];
#pragma unroll
      for (int r = 0; r < 4; ++r) {
        float4 xv = *(const float4*)&Xl[(g * 4 + r) * 128 + k4];
        acc[r] = fmaf(xv.x, w0, fmaf(xv.y, w1, fmaf(xv.z, w2, fmaf(xv.w, w3, acc[r]))));
      }
    }
#pragma unroll
    for (int r = 0; r < 4; ++r)
      Y[(row0 + g * 4 + r) * COUT + ch * 64 + col] = acc[r];
  }
}

// out[i][c] = bias[c] + h[i][c] * dinv[i]^2   (bias + self-loop message)
template <int C>
__global__ void k_agg_init(const float* __restrict__ h, const float* __restrict__ dinv,
                           const float* __restrict__ bias, float* __restrict__ out) {
  long t = (long)blockIdx.x * 256 + threadIdx.x;
  constexpr int TP = C / 4;
  int i = (int)(t / TP);
  if (i >= NN) return;
  int c4 = (int)(t % TP) * 4;
  float di = dinv[i];
  float nn = di * di;
  float4 hv = *(const float4*)&h[(long)i * C + c4];
  float4 bv = *(const float4*)&bias[c4];
  float4 o;
  o.x = bv.x + hv.x * nn;
  o.y = bv.y + hv.y * nn;
  o.z = bv.z + hv.z * nn;
  o.w = bv.w + hv.w * nn;
  *(float4*)&out[(long)i * C + c4] = o;
}

// edge-parallel scatter: out[d] += h[s] * dinv[s]*dinv[d]
template <int C>
__global__ void k_agg_edges(const void* __restrict__ e, const int* __restrict__ flag,
                            int E, const float* __restrict__ h,
                            const float* __restrict__ dinv, float* __restrict__ out) {
  long t = (long)blockIdx.x * 256 + threadIdx.x;
  constexpr int TP = C / 4;  // threads per edge
  long eid = t / TP;
  if (eid >= E) return;
  int c4 = (int)(t % TP) * 4;
  int is64 = *flag;
  int s = eload(e, eid, is64);
  int d = eload(e, (long)E + eid, is64);
  float nrm = dinv[s] * dinv[d];
  float4 hv = *(const float4*)&h[(long)s * C + c4];
  float* o = &out[(long)d * C + c4];
  atomicAdd(o + 0, hv.x * nrm);
  atomicAdd(o + 1, hv.y * nrm);
  atomicAdd(o + 2, hv.z * nrm);
  atomicAdd(o + 3, hv.w * nrm);
}

extern "C" void kernel_launch(void* const* d_in, const int* in_sizes, int n_in,
                              void* d_out, int out_size, void* d_ws, size_t ws_size,
                              hipStream_t stream) {
  const float* x  = (const float*)d_in[0];
  const void*  ep = d_in[1];
  const float* W1 = (const float*)d_in[2];
  const float* b1 = (const float*)d_in[3];
  const float* W2 = (const float*)d_in[4];
  const float* b2 = (const float*)d_in[5];
  float* out = (float*)d_out;
  const int E = in_sizes[1] / 2;

  float* wsf  = (float*)d_ws;
  int*   flag = (int*)d_ws;
  float* dinv = wsf + 64;
  float* h1   = wsf + 100160;                 // 256B-aligned region
  float* a1   = h1 + (long)NN * 128;
  float* h2   = h1;                           // h1 dead once a1 is built

  k_detect<<<1, 64, 0, stream>>>((const unsigned*)ep, flag);
  k_deg_init<<<(NN + 255) / 256, 256, 0, stream>>>(dinv);
  k_deg_accum<<<(E + 255) / 256, 256, 0, stream>>>(ep, flag, E, dinv);
  k_rsqrt<<<(NN + 255) / 256, 256, 0, stream>>>(dinv);

  // layer 1
  gemm_x_w<128, false><<<NN / 16, 256, 0, stream>>>(x, W1, h1);
  k_agg_init<128><<<(NN * 32 + 255) / 256, 256, 0, stream>>>(h1, dinv, b1, a1);
  {
    long threads = (long)E * 32;
    k_agg_edges<128><<<(unsigned)((threads + 255) / 256), 256, 0, stream>>>(
        ep, flag, E, h1, dinv, a1);
  }

  // layer 2 (relu fused into GEMM input load)
  gemm_x_w<64, true><<<NN / 16, 256, 0, stream>>>(a1, W2, h2);
  k_agg_init<64><<<(NN * 16 + 255) / 256, 256, 0, stream>>>(h2, dinv, b2, out);
  {
    long threads = (long)E * 16;
    k_agg_edges<64><<<(unsigned)((threads + 255) / 256), 256, 0, stream>>>(
        ep, flag, E, h2, dinv, out);
  }
}

// Round 2
// 629.574 us; speedup vs baseline: 6.9974x; 6.9974x over previous
//
#include <hip/hip_runtime.h>

#define NN 100000

// ---------------------------------------------------------------------------
// Edge index may arrive as int32 (harness doc) or int64 (reference dtype).
// Detect at runtime: for int64 little-endian, every odd 32-bit word is the
// high word of a value < 100000 => zero.
// ---------------------------------------------------------------------------
__device__ __forceinline__ int eload(const void* e, long i, int is64) {
  if (is64) return (int)((const long long*)e)[i];
  return ((const int*)e)[i];
}

__global__ void k_detect(const unsigned* __restrict__ e, int* __restrict__ flag) {
  if (threadIdx.x == 0 && blockIdx.x == 0) {
    unsigned acc = 0;
    for (int i = 1; i < 4096; i += 2) acc |= e[i];
    *flag = (acc == 0) ? 1 : 0;  // 1 => int64
  }
}

__global__ void k_zero(int* __restrict__ p, int n) {
  int i = blockIdx.x * 256 + threadIdx.x;
  if (i < n) p[i] = 0;
}

__global__ void k_hist(const void* __restrict__ e, const int* __restrict__ flag,
                       int E, int* __restrict__ counts) {
  int t = blockIdx.x * 256 + threadIdx.x;
  if (t < E) {
    int d = eload(e, (long)E + t, *flag);
    atomicAdd(&counts[d], 1);
  }
}

__global__ void k_dinv(const int* __restrict__ counts, float* __restrict__ dinv) {
  int i = blockIdx.x * 256 + threadIdx.x;
  if (i < NN) dinv[i] = rsqrtf((float)counts[i] + 1.0f);  // +1 self-loop
}

// ---- 3-kernel exclusive scan of counts[NN] -> rowptr ----------------------
__global__ __launch_bounds__(512) void k_scan1(const int* __restrict__ counts,
                                               int* __restrict__ rowptr,
                                               int* __restrict__ bsum) {
  __shared__ int sm[512];
  int tid = threadIdx.x;
  int i = blockIdx.x * 512 + tid;
  int v = (i < NN) ? counts[i] : 0;
  sm[tid] = v;
  __syncthreads();
  for (int off = 1; off < 512; off <<= 1) {
    int t = (tid >= off) ? sm[tid - off] : 0;
    __syncthreads();
    sm[tid] += t;
    __syncthreads();
  }
  if (i < NN) rowptr[i] = sm[tid] - v;  // exclusive within block
  if (tid == 511) bsum[blockIdx.x] = sm[tid];
}

__global__ void k_scan2(int* __restrict__ bsum, int nb) {
  if (threadIdx.x == 0 && blockIdx.x == 0) {
    int run = 0;
    for (int b = 0; b < nb; ++b) {
      int v = bsum[b];
      bsum[b] = run;
      run += v;
    }
  }
}

__global__ __launch_bounds__(512) void k_scan3(int* __restrict__ rowptr,
                                               int* __restrict__ cursor,
                                               const int* __restrict__ bsum, int E) {
  int i = blockIdx.x * 512 + threadIdx.x;
  if (i < NN) {
    int v = rowptr[i] + bsum[blockIdx.x];
    rowptr[i] = v;
    cursor[i] = v;
  }
  if (i == 0) rowptr[NN] = E;
}

__global__ void k_scatter(const void* __restrict__ e, const int* __restrict__ flag,
                          int E, int* __restrict__ cursor, int* __restrict__ csr) {
  int t = blockIdx.x * 256 + threadIdx.x;
  if (t < E) {
    int is64 = *flag;
    int s = eload(e, t, is64);
    int d = eload(e, (long)E + t, is64);
    int pos = atomicAdd(&cursor[d], 1);
    csr[pos] = s;
  }
}

// ---------------------------------------------------------------------------
// Y[N x COUT] = (relu?)(X[N x 128]) @ W[128 x COUT], epilogue scale by dinv[row]
// -> produces hn = h * dinv (per-row), feeding the gather aggregation.
// ---------------------------------------------------------------------------
template <int COUT, bool RELU>
__global__ __launch_bounds__(256) void gemm_x_w(const float* __restrict__ X,
                                                const float* __restrict__ W,
                                                const float* __restrict__ dinv,
                                                float* __restrict__ Y) {
  __shared__ float Wl[128 * 64];
  __shared__ float Xl[16 * 128];
  const int tid = threadIdx.x;
  const long row0 = (long)blockIdx.x * 16;

  for (int i = tid; i < 512; i += 256) {
    int r = i >> 5, c4 = (i & 31) << 2;
    float4 v = *(const float4*)&X[(row0 + r) * 128 + c4];
    if (RELU) {
      v.x = fmaxf(v.x, 0.f); v.y = fmaxf(v.y, 0.f);
      v.z = fmaxf(v.z, 0.f); v.w = fmaxf(v.w, 0.f);
    }
    *(float4*)&Xl[r * 128 + c4] = v;
  }

  const int col = tid & 63;
  const int g = tid >> 6;  // 0..3, 4 rows each

  for (int ch = 0; ch < COUT / 64; ++ch) {
    __syncthreads();
    for (int i = tid; i < 2048; i += 256) {
      int k = i >> 4, c4 = (i & 15) << 2;
      *(float4*)&Wl[k * 64 + c4] = *(const float4*)&W[(long)k * COUT + ch * 64 + c4];
    }
    __syncthreads();

    float acc[4] = {0.f, 0.f, 0.f, 0.f};
#pragma unroll 4
    for (int k4 = 0; k4 < 128; k4 += 4) {
      float w0 = Wl[(k4 + 0) * 64 + col];
      float w1 = Wl[(k4 + 1) * 64 + col];
      float w2 = Wl[(k4 + 2) * 64 + col];
      float w3 = Wl[(k4 + 3) * 64 + col];
#pragma unroll
      for (int r = 0; r < 4; ++r) {
        float4 xv = *(const float4*)&Xl[(g * 4 + r) * 128 + k4];
        acc[r] = fmaf(xv.x, w0, fmaf(xv.y, w1, fmaf(xv.z, w2, fmaf(xv.w, w3, acc[r]))));
      }
    }
#pragma unroll
    for (int r = 0; r < 4; ++r) {
      float dd = dinv[row0 + g * 4 + r];
      Y[(row0 + g * 4 + r) * COUT + ch * 64 + col] = acc[r] * dd;
    }
  }
}

// ---------------------------------------------------------------------------
// Gather aggregation: out[d] = dinv[d] * (hn[d] + sum_{s in N(d)} hn[s]) + bias
// TP = C/4 threads per node, float4 per thread, no atomics.
// ---------------------------------------------------------------------------
template <int C>
__global__ __launch_bounds__(256) void k_agg_csr(const float* __restrict__ hn,
                                                 const int* __restrict__ rowptr,
                                                 const int* __restrict__ csr,
                                                 const float* __restrict__ dinv,
                                                 const float* __restrict__ bias,
                                                 float* __restrict__ out) {
  constexpr int TP = C / 4;
  long t = (long)blockIdx.x * 256 + threadIdx.x;
  int d = (int)(t / TP);
  if (d >= NN) return;
  int c4 = (int)(t % TP) * 4;

  float4 acc = *(const float4*)&hn[(long)d * C + c4];  // self-loop message
  int e = rowptr[d];
  const int end = rowptr[d + 1];

  for (; e + 4 <= end; e += 4) {
    int s0 = csr[e], s1 = csr[e + 1], s2 = csr[e + 2], s3 = csr[e + 3];
    float4 v0 = *(const float4*)&hn[(long)s0 * C + c4];
    float4 v1 = *(const float4*)&hn[(long)s1 * C + c4];
    float4 v2 = *(const float4*)&hn[(long)s2 * C + c4];
    float4 v3 = *(const float4*)&hn[(long)s3 * C + c4];
    acc.x += (v0.x + v1.x) + (v2.x + v3.x);
    acc.y += (v0.y + v1.y) + (v2.y + v3.y);
    acc.z += (v0.z + v1.z) + (v2.z + v3.z);
    acc.w += (v0.w + v1.w) + (v2.w + v3.w);
  }
  for (; e < end; ++e) {
    int s = csr[e];
    float4 v = *(const float4*)&hn[(long)s * C + c4];
    acc.x += v.x; acc.y += v.y; acc.z += v.z; acc.w += v.w;
  }

  float dd = dinv[d];
  float4 bv = *(const float4*)&bias[c4];
  float4 o;
  o.x = acc.x * dd + bv.x;
  o.y = acc.y * dd + bv.y;
  o.z = acc.z * dd + bv.z;
  o.w = acc.w * dd + bv.w;
  *(float4*)&out[(long)d * C + c4] = o;
}

extern "C" void kernel_launch(void* const* d_in, const int* in_sizes, int n_in,
                              void* d_out, int out_size, void* d_ws, size_t ws_size,
                              hipStream_t stream) {
  const float* x  = (const float*)d_in[0];
  const void*  ep = d_in[1];
  const float* W1 = (const float*)d_in[2];
  const float* b1 = (const float*)d_in[3];
  const float* W2 = (const float*)d_in[4];
  const float* b2 = (const float*)d_in[5];
  float* out = (float*)d_out;
  const int E = in_sizes[1] / 2;

  // workspace layout (float/int element offsets from base)
  float* wsf    = (float*)d_ws;
  int*   wsi    = (int*)d_ws;
  int*   flag   = wsi;                    // 1
  float* dinv   = wsf + 64;               // 100000 f
  int*   counts = wsi + 100096;           // 100000 i (reused as cursor)
  int*   rowptr = wsi + 200128;           // 100001 i
  int*   bsum   = wsi + 300160;           // 256 i
  int*   csr    = wsi + 300416;           // 1600000 i
  float* h1     = wsf + 1900416;          // 12.8M f
  float* a1     = h1 + (long)NN * 128;    // 12.8M f
  float* h2     = h1;                     // h1 dead once a1 built
  int*   cursor = counts;                 // counts dead after dinv+scan1

  const int NB = (NN + 511) / 512;  // 196

  k_detect<<<1, 64, 0, stream>>>((const unsigned*)ep, flag);
  k_zero<<<(NN + 255) / 256, 256, 0, stream>>>(counts, NN);
  k_hist<<<(E + 255) / 256, 256, 0, stream>>>(ep, flag, E, counts);
  k_dinv<<<(NN + 255) / 256, 256, 0, stream>>>(counts, dinv);
  k_scan1<<<NB, 512, 0, stream>>>(counts, rowptr, bsum);
  k_scan2<<<1, 64, 0, stream>>>(bsum, NB);
  k_scan3<<<NB, 512, 0, stream>>>(rowptr, cursor, bsum, E);
  k_scatter<<<(E + 255) / 256, 256, 0, stream>>>(ep, flag, E, cursor, csr);

  // layer 1: hn1 = (x @ W1) * dinv ; a1 = dinv*(hn1_self + gather) + b1
  gemm_x_w<128, false><<<NN / 16, 256, 0, stream>>>(x, W1, dinv, h1);
  k_agg_csr<128><<<(NN * 32) / 256, 256, 0, stream>>>(h1, rowptr, csr, dinv, b1, a1);

  // layer 2: hn2 = relu(a1) @ W2 * dinv ; out = dinv*(hn2_self + gather) + b2
  gemm_x_w<64, true><<<NN / 16, 256, 0, stream>>>(a1, W2, dinv, h2);
  k_agg_csr<64><<<(NN * 16) / 256, 256, 0, stream>>>(h2, rowptr, csr, dinv, b2, out);
}

// Round 3
// 536.197 us; speedup vs baseline: 8.2160x; 1.1741x over previous
//
#include <hip/hip_runtime.h>
#include <hip/hip_fp16.h>

#define NN 100000
#define WIN 12500          // dst nodes per bucket (8 buckets)
#define CAP 204800         // pair capacity per bucket (200k mean, +11 sigma)
#define EPB 16             // edges per thread in phase A

// ---------------------------------------------------------------------------
// Edge index may arrive as int32 or int64; detect via odd 32-bit words == 0.
// ---------------------------------------------------------------------------
__device__ __forceinline__ int eload(const void* e, long i, int is64) {
  if (is64) return (int)((const long long*)e)[i];
  return ((const int*)e)[i];
}

__global__ void k_detect(const unsigned* __restrict__ e, int* __restrict__ flag) {
  if (threadIdx.x == 0 && blockIdx.x == 0) {
    unsigned acc = 0;
    for (int i = 1; i < 4096; i += 2) acc |= e[i];
    *flag = (acc == 0) ? 1 : 0;  // 1 => int64
  }
}

__global__ void k_init8(int* __restrict__ bcur) {
  int i = threadIdx.x;
  if (i < 8) bcur[i] = i * CAP;
}

__global__ void k_zero(int* __restrict__ p, int n) {
  int i = blockIdx.x * 256 + threadIdx.x;
  if (i < n) p[i] = 0;
}

// ---------------------------------------------------------------------------
// Phase A: multi-split edges into 8 dst-range buckets with coalesced writes.
// Per-thread counts packed 4x16-bit per uint64 (2 regs), block LDS scan,
// one global atomicAdd per bucket per block.
// ---------------------------------------------------------------------------
__global__ __launch_bounds__(256) void k_bucket(const void* __restrict__ e,
                                                const int* __restrict__ flag,
                                                int E, int* __restrict__ bcur,
                                                int2* __restrict__ pairs) {
  __shared__ unsigned long long sA[256], sB[256];
  __shared__ int bases[8];
  const int tid = threadIdx.x;
  const long base = (long)blockIdx.x * (256 * EPB);
  const int is64 = *flag;

  int sv[EPB], dv[EPB];
  unsigned long long c01 = 0, c23 = 0;
#pragma unroll
  for (int j = 0; j < EPB; ++j) {
    long idx = base + j * 256 + tid;
    int s = 0, d = -1;
    if (idx < E) {
      s = eload(e, idx, is64);
      d = eload(e, (long)E + idx, is64);
    }
    sv[j] = s; dv[j] = d;
    if (d >= 0) {
      int b = (unsigned)d / WIN;
      if (b < 4) c01 += 1ull << (16 * b);
      else       c23 += 1ull << (16 * (b - 4));
    }
  }
  sA[tid] = c01; sB[tid] = c23;
  __syncthreads();
  for (int off = 1; off < 256; off <<= 1) {
    unsigned long long a = (tid >= off) ? sA[tid - off] : 0;
    unsigned long long b = (tid >= off) ? sB[tid - off] : 0;
    __syncthreads();
    sA[tid] += a; sB[tid] += b;
    __syncthreads();
  }
  const unsigned long long eA = sA[tid] - c01;  // exclusive prefix for this thread
  const unsigned long long eB = sB[tid] - c23;
  if (tid == 0) {
    unsigned long long tA = sA[255], tB = sB[255];
#pragma unroll
    for (int b = 0; b < 4; ++b)
      bases[b] = atomicAdd(&bcur[b], (int)((tA >> (16 * b)) & 0xffff));
#pragma unroll
    for (int b = 4; b < 8; ++b)
      bases[b] = atomicAdd(&bcur[b], (int)((tB >> (16 * (b - 4))) & 0xffff));
  }
  __syncthreads();

  unsigned long long r01 = 0, r23 = 0;
#pragma unroll
  for (int j = 0; j < EPB; ++j) {
    int d = dv[j];
    if (d < 0) continue;
    int b = (unsigned)d / WIN;
    int off;
    if (b < 4) {
      int sh = 16 * b;
      off = (int)(((eA + r01) >> sh) & 0xffff);
      r01 += 1ull << sh;
    } else {
      int sh = 16 * (b - 4);
      off = (int)(((eB + r23) >> sh) & 0xffff);
      r23 += 1ull << sh;
    }
    pairs[bases[b] + off] = make_int2(sv[j], d);
  }
}

// ---------------------------------------------------------------------------
// Phase B: block b handles bucket b&7 (round-robin blockIdx->XCD keeps the
// 0.85MB counts/cursor/csr window resident in ONE XCD's L2).
// ---------------------------------------------------------------------------
__global__ __launch_bounds__(256) void k_hist_b(const int2* __restrict__ pairs,
                                                const int* __restrict__ bcur,
                                                int* __restrict__ counts) {
  const int w = blockIdx.x & 7;
  const int slice = blockIdx.x >> 3;
  const int nsl = gridDim.x >> 3;
  const int cnt = bcur[w] - w * CAP;
  const long b0 = (long)w * CAP;
  const long lo = b0 + (long)slice * cnt / nsl;
  const long hi = b0 + (long)(slice + 1) * cnt / nsl;
  for (long i = lo + threadIdx.x; i < hi; i += 256)
    atomicAdd(&counts[pairs[i].y], 1);
}

__global__ __launch_bounds__(256) void k_scatter_b(const int2* __restrict__ pairs,
                                                   const int* __restrict__ bcur,
                                                   int* __restrict__ cursor,
                                                   int* __restrict__ csr) {
  const int w = blockIdx.x & 7;
  const int slice = blockIdx.x >> 3;
  const int nsl = gridDim.x >> 3;
  const int cnt = bcur[w] - w * CAP;
  const long b0 = (long)w * CAP;
  const long lo = b0 + (long)slice * cnt / nsl;
  const long hi = b0 + (long)(slice + 1) * cnt / nsl;
  for (long i = lo + threadIdx.x; i < hi; i += 256) {
    int2 p = pairs[i];
    int pos = atomicAdd(&cursor[p.y], 1);
    csr[pos] = p.x;
  }
}

__global__ void k_dinv(const int* __restrict__ counts, float* __restrict__ dinv) {
  int i = blockIdx.x * 256 + threadIdx.x;
  if (i < NN) dinv[i] = rsqrtf((float)counts[i] + 1.0f);  // +1 self-loop
}

// ---- 3-kernel exclusive scan of counts[NN] -> rowptr ----------------------
__global__ __launch_bounds__(512) void k_scan1(const int* __restrict__ counts,
                                               int* __restrict__ rowptr,
                                               int* __restrict__ bsum) {
  __shared__ int sm[512];
  int tid = threadIdx.x;
  int i = blockIdx.x * 512 + tid;
  int v = (i < NN) ? counts[i] : 0;
  sm[tid] = v;
  __syncthreads();
  for (int off = 1; off < 512; off <<= 1) {
    int t = (tid >= off) ? sm[tid - off] : 0;
    __syncthreads();
    sm[tid] += t;
    __syncthreads();
  }
  if (i < NN) rowptr[i] = sm[tid] - v;
  if (tid == 511) bsum[blockIdx.x] = sm[tid];
}

__global__ void k_scan2(int* __restrict__ bsum, int nb) {
  if (threadIdx.x == 0 && blockIdx.x == 0) {
    int run = 0;
    for (int b = 0; b < nb; ++b) { int v = bsum[b]; bsum[b] = run; run += v; }
  }
}

__global__ __launch_bounds__(512) void k_scan3(int* __restrict__ rowptr,
                                               int* __restrict__ cursor,
                                               const int* __restrict__ bsum, int E) {
  int i = blockIdx.x * 512 + threadIdx.x;
  if (i < NN) {
    int v = rowptr[i] + bsum[blockIdx.x];
    rowptr[i] = v;
    cursor[i] = v;
  }
  if (i == 0) rowptr[NN] = E;
}

// ---------------------------------------------------------------------------
// Y[N x COUT] = (relu?)(X[N x 128]) @ W[128 x COUT], epilogue *dinv[row].
// TIN: float or __half.  TOUT: float or __half.
// ---------------------------------------------------------------------------
template <int COUT, bool RELU, typename TIN, typename TOUT>
__global__ __launch_bounds__(256) void gemm_x_w(const TIN* __restrict__ X,
                                                const float* __restrict__ W,
                                                const float* __restrict__ dinv,
                                                TOUT* __restrict__ Y) {
  __shared__ float Wl[128 * 64];
  __shared__ float Xl[16 * 128];
  const int tid = threadIdx.x;
  const long row0 = (long)blockIdx.x * 16;

  if constexpr (sizeof(TIN) == 4) {
    for (int i = tid; i < 512; i += 256) {
      int r = i >> 5, c4 = (i & 31) << 2;
      float4 v = *(const float4*)&X[(row0 + r) * 128 + c4];
      if (RELU) {
        v.x = fmaxf(v.x, 0.f); v.y = fmaxf(v.y, 0.f);
        v.z = fmaxf(v.z, 0.f); v.w = fmaxf(v.w, 0.f);
      }
      *(float4*)&Xl[r * 128 + c4] = v;
    }
  } else {
    int r = tid >> 4, c8 = (tid & 15) << 3;  // 256 threads x 8 halves = 2048
    float4 raw = *(const float4*)&X[(row0 + r) * 128 + c8];
    const __half2* h2 = (const __half2*)&raw;
#pragma unroll
    for (int q = 0; q < 4; ++q) {
      float2 f = __half22float2(h2[q]);
      if (RELU) { f.x = fmaxf(f.x, 0.f); f.y = fmaxf(f.y, 0.f); }
      Xl[r * 128 + c8 + 2 * q]     = f.x;
      Xl[r * 128 + c8 + 2 * q + 1] = f.y;
    }
  }

  const int col = tid & 63;
  const int g = tid >> 6;

  for (int ch = 0; ch < COUT / 64; ++ch) {
    __syncthreads();
    for (int i = tid; i < 2048; i += 256) {
      int k = i >> 4, c4 = (i & 15) << 2;
      *(float4*)&Wl[k * 64 + c4] = *(const float4*)&W[(long)k * COUT + ch * 64 + c4];
    }
    __syncthreads();

    float acc[4] = {0.f, 0.f, 0.f, 0.f};
#pragma unroll 4
    for (int k4 = 0; k4 < 128; k4 += 4) {
      float w0 = Wl[(k4 + 0) * 64 + col];
      float w1 = Wl[(k4 + 1) * 64 + col];
      float w2 = Wl[(k4 + 2) * 64 + col];
      float w3 = Wl[(k4 + 3) * 64 + col];
#pragma unroll
      for (int r = 0; r < 4; ++r) {
        float4 xv = *(const float4*)&Xl[(g * 4 + r) * 128 + k4];
        acc[r] = fmaf(xv.x, w0, fmaf(xv.y, w1, fmaf(xv.z, w2, fmaf(xv.w, w3, acc[r]))));
      }
    }
#pragma unroll
    for (int r = 0; r < 4; ++r) {
      float dd = dinv[row0 + g * 4 + r];
      float o = acc[r] * dd;
      if constexpr (sizeof(TOUT) == 2)
        Y[(row0 + g * 4 + r) * COUT + ch * 64 + col] = __float2half(o);
      else
        Y[(row0 + g * 4 + r) * COUT + ch * 64 + col] = o;
    }
  }
}

// ---------------------------------------------------------------------------
// Gather: out[d] = dinv[d]*(hn[d] + sum_{s in N(d)} hn[s]) + bias.
// hn is fp16; accumulate fp32. TP = C/8 threads/node, 16B loads.
// ---------------------------------------------------------------------------
template <int C, typename TOUT>
__global__ __launch_bounds__(256) void k_agg_csr(const __half* __restrict__ hn,
                                                 const int* __restrict__ rowptr,
                                                 const int* __restrict__ csr,
                                                 const float* __restrict__ dinv,
                                                 const float* __restrict__ bias,
                                                 TOUT* __restrict__ out) {
  constexpr int TP = C / 8;
  long t = (long)blockIdx.x * 256 + threadIdx.x;
  int d = (int)(t / TP);
  if (d >= NN) return;
  int c8 = (int)(t % TP) * 8;

  float acc[8];
  {
    float4 raw = *(const float4*)&hn[(long)d * C + c8];
    const __half2* h2 = (const __half2*)&raw;
#pragma unroll
    for (int q = 0; q < 4; ++q) {
      float2 f = __half22float2(h2[q]);
      acc[2 * q] = f.x; acc[2 * q + 1] = f.y;
    }
  }
  int e = rowptr[d];
  const int end = rowptr[d + 1];

  for (; e + 4 <= end; e += 4) {
    int s0 = csr[e], s1 = csr[e + 1], s2 = csr[e + 2], s3 = csr[e + 3];
    float4 r0 = *(const float4*)&hn[(long)s0 * C + c8];
    float4 r1 = *(const float4*)&hn[(long)s1 * C + c8];
    float4 r2 = *(const float4*)&hn[(long)s2 * C + c8];
    float4 r3 = *(const float4*)&hn[(long)s3 * C + c8];
    const __half2* a0 = (const __half2*)&r0;
    const __half2* a1 = (const __half2*)&r1;
    const __half2* a2 = (const __half2*)&r2;
    const __half2* a3 = (const __half2*)&r3;
#pragma unroll
    for (int q = 0; q < 4; ++q) {
      float2 f0 = __half22float2(a0[q]);
      float2 f1 = __half22float2(a1[q]);
      float2 f2 = __half22float2(a2[q]);
      float2 f3 = __half22float2(a3[q]);
      acc[2 * q]     += (f0.x + f1.x) + (f2.x + f3.x);
      acc[2 * q + 1] += (f0.y + f1.y) + (f2.y + f3.y);
    }
  }
  for (; e < end; ++e) {
    int s = csr[e];
    float4 r0 = *(const float4*)&hn[(long)s * C + c8];
    const __half2* a0 = (const __half2*)&r0;
#pragma unroll
    for (int q = 0; q < 4; ++q) {
      float2 f0 = __half22float2(a0[q]);
      acc[2 * q] += f0.x; acc[2 * q + 1] += f0.y;
    }
  }

  float dd = dinv[d];
  float4 b0 = *(const float4*)&bias[c8];
  float4 b1 = *(const float4*)&bias[c8 + 4];
  float o[8];
  o[0] = acc[0] * dd + b0.x; o[1] = acc[1] * dd + b0.y;
  o[2] = acc[2] * dd + b0.z; o[3] = acc[3] * dd + b0.w;
  o[4] = acc[4] * dd + b1.x; o[5] = acc[5] * dd + b1.y;
  o[6] = acc[6] * dd + b1.z; o[7] = acc[7] * dd + b1.w;

  if constexpr (sizeof(TOUT) == 2) {
    __half2 hp[4];
    hp[0] = __floats2half2_rn(o[0], o[1]);
    hp[1] = __floats2half2_rn(o[2], o[3]);
    hp[2] = __floats2half2_rn(o[4], o[5]);
    hp[3] = __floats2half2_rn(o[6], o[7]);
    *(float4*)&out[(long)d * C + c8] = *(float4*)hp;
  } else {
    *(float4*)&out[(long)d * C + c8]     = make_float4(o[0], o[1], o[2], o[3]);
    *(float4*)&out[(long)d * C + c8 + 4] = make_float4(o[4], o[5], o[6], o[7]);
  }
}

extern "C" void kernel_launch(void* const* d_in, const int* in_sizes, int n_in,
                              void* d_out, int out_size, void* d_ws, size_t ws_size,
                              hipStream_t stream) {
  const float* x  = (const float*)d_in[0];
  const void*  ep = d_in[1];
  const float* W1 = (const float*)d_in[2];
  const float* b1 = (const float*)d_in[3];
  const float* W2 = (const float*)d_in[4];
  const float* b2 = (const float*)d_in[5];
  float* out = (float*)d_out;
  const int E = in_sizes[1] / 2;

  // workspace layout (int-element offsets from base)
  float*  wsf    = (float*)d_ws;
  int*    wsi    = (int*)d_ws;
  int*    flag   = wsi;                        // [0]
  int*    bcur   = wsi + 16;                   // 8
  float*  dinv   = wsf + 64;                   // 100000 f
  int*    counts = wsi + 100096;               // 100000 (reused as cursor)
  int*    rowptr = wsi + 200128;               // 100001
  int*    bsum   = wsi + 300160;               // 256
  int*    csr    = wsi + 300416;               // 1600000
  int2*   pairs  = (int2*)(wsi + 1900416);     // 8*CAP int2 = 13.1MB
  __half* hn1    = (__half*)(wsi + 5177216);   // 12.8M halves
  __half* a1     = (__half*)((char*)d_ws + 46308864);  // 12.8M halves
  __half* hn2    = hn1;                        // hn1 dead once a1 built
  int*    cursor = counts;

  const int NB = (NN + 511) / 512;             // 196
  const int ABLK = (E + 256 * EPB - 1) / (256 * EPB);

  k_detect<<<1, 64, 0, stream>>>((const unsigned*)ep, flag);
  k_init8<<<1, 64, 0, stream>>>(bcur);
  k_zero<<<(NN + 255) / 256, 256, 0, stream>>>(counts, NN);
  k_bucket<<<ABLK, 256, 0, stream>>>(ep, flag, E, bcur, pairs);
  k_hist_b<<<2048, 256, 0, stream>>>(pairs, bcur, counts);
  k_dinv<<<(NN + 255) / 256, 256, 0, stream>>>(counts, dinv);
  k_scan1<<<NB, 512, 0, stream>>>(counts, rowptr, bsum);
  k_scan2<<<1, 64, 0, stream>>>(bsum, NB);
  k_scan3<<<NB, 512, 0, stream>>>(rowptr, cursor, bsum, E);
  k_scatter_b<<<2048, 256, 0, stream>>>(pairs, bcur, cursor, csr);

  // layer 1
  gemm_x_w<128, false, float, __half><<<NN / 16, 256, 0, stream>>>(x, W1, dinv, hn1);
  k_agg_csr<128, __half><<<(NN * 16) / 256, 256, 0, stream>>>(hn1, rowptr, csr, dinv, b1, a1);

  // layer 2
  gemm_x_w<64, true, __half, __half><<<NN / 16, 256, 0, stream>>>(a1, W2, dinv, hn2);
  k_agg_csr<64, float><<<(NN * 8) / 256, 256, 0, stream>>>(hn2, rowptr, csr, dinv, b2, out);
}

// Round 4
// 358.283 us; speedup vs baseline: 12.2958x; 1.4966x over previous
//
#include <hip/hip_runtime.h>
#include <hip/hip_fp16.h>

#define NN 100000
#define WIN 12500          // dst nodes per bucket (8 buckets)
#define CAP 204800         // pair capacity per bucket
#define EPB 16             // edges per thread in phase A

typedef _Float16 f16;
typedef _Float16 f16x8 __attribute__((ext_vector_type(8)));
typedef float f32x4 __attribute__((ext_vector_type(4)));

// ---------------------------------------------------------------------------
// Edge index may arrive as int32 or int64; detect via odd 32-bit words == 0.
// Parallel: 1024 threads x 2 words, LDS OR-reduce.
// ---------------------------------------------------------------------------
__device__ __forceinline__ int eload(const void* e, long i, int is64) {
  if (is64) return (int)((const long long*)e)[i];
  return ((const int*)e)[i];
}

__global__ __launch_bounds__(1024) void k_detect(const unsigned* __restrict__ e,
                                                 int* __restrict__ flag) {
  __shared__ unsigned red[1024];
  int t = threadIdx.x;
  unsigned acc = e[1 + 2 * t] | e[1 + 2 * t + 2048];
  red[t] = acc;
  __syncthreads();
  for (int off = 512; off > 0; off >>= 1) {
    if (t < off) red[t] |= red[t + off];
    __syncthreads();
  }
  if (t == 0) *flag = (red[0] == 0) ? 1 : 0;  // 1 => int64
}

__global__ void k_init8(int* __restrict__ bcur) {
  int i = threadIdx.x;
  if (i < 8) bcur[i] = i * CAP;
}

__global__ void k_zero(int* __restrict__ p, int n) {
  int i = blockIdx.x * 256 + threadIdx.x;
  if (i < n) p[i] = 0;
}

// ---------------------------------------------------------------------------
// Phase A: multi-split edges into 8 dst-range buckets with coalesced writes.
// ---------------------------------------------------------------------------
__global__ __launch_bounds__(256) void k_bucket(const void* __restrict__ e,
                                                const int* __restrict__ flag,
                                                int E, int* __restrict__ bcur,
                                                int2* __restrict__ pairs) {
  __shared__ unsigned long long sA[256], sB[256];
  __shared__ int bases[8];
  const int tid = threadIdx.x;
  const long base = (long)blockIdx.x * (256 * EPB);
  const int is64 = *flag;

  int sv[EPB], dv[EPB];
  unsigned long long c01 = 0, c23 = 0;
#pragma unroll
  for (int j = 0; j < EPB; ++j) {
    long idx = base + j * 256 + tid;
    int s = 0, d = -1;
    if (idx < E) {
      s = eload(e, idx, is64);
      d = eload(e, (long)E + idx, is64);
    }
    sv[j] = s; dv[j] = d;
    if (d >= 0) {
      int b = (unsigned)d / WIN;
      if (b < 4) c01 += 1ull << (16 * b);
      else       c23 += 1ull << (16 * (b - 4));
    }
  }
  sA[tid] = c01; sB[tid] = c23;
  __syncthreads();
  for (int off = 1; off < 256; off <<= 1) {
    unsigned long long a = (tid >= off) ? sA[tid - off] : 0;
    unsigned long long b = (tid >= off) ? sB[tid - off] : 0;
    __syncthreads();
    sA[tid] += a; sB[tid] += b;
    __syncthreads();
  }
  const unsigned long long eA = sA[tid] - c01;
  const unsigned long long eB = sB[tid] - c23;
  if (tid == 0) {
    unsigned long long tA = sA[255], tB = sB[255];
#pragma unroll
    for (int b = 0; b < 4; ++b)
      bases[b] = atomicAdd(&bcur[b], (int)((tA >> (16 * b)) & 0xffff));
#pragma unroll
    for (int b = 4; b < 8; ++b)
      bases[b] = atomicAdd(&bcur[b], (int)((tB >> (16 * (b - 4))) & 0xffff));
  }
  __syncthreads();

  unsigned long long r01 = 0, r23 = 0;
#pragma unroll
  for (int j = 0; j < EPB; ++j) {
    int d = dv[j];
    if (d < 0) continue;
    int b = (unsigned)d / WIN;
    int off;
    if (b < 4) {
      int sh = 16 * b;
      off = (int)(((eA + r01) >> sh) & 0xffff);
      r01 += 1ull << sh;
    } else {
      int sh = 16 * (b - 4);
      off = (int)(((eB + r23) >> sh) & 0xffff);
      r23 += 1ull << sh;
    }
    pairs[bases[b] + off] = make_int2(sv[j], d);
  }
}

// ---------------------------------------------------------------------------
// Phase B: block b handles bucket b&7 (XCD-local window).
// ---------------------------------------------------------------------------
__global__ __launch_bounds__(256) void k_hist_b(const int2* __restrict__ pairs,
                                                const int* __restrict__ bcur,
                                                int* __restrict__ counts) {
  const int w = blockIdx.x & 7;
  const int slice = blockIdx.x >> 3;
  const int nsl = gridDim.x >> 3;
  const int cnt = bcur[w] - w * CAP;
  const long b0 = (long)w * CAP;
  const long lo = b0 + (long)slice * cnt / nsl;
  const long hi = b0 + (long)(slice + 1) * cnt / nsl;
  for (long i = lo + threadIdx.x; i < hi; i += 256)
    atomicAdd(&counts[pairs[i].y], 1);
}

__global__ __launch_bounds__(256) void k_scatter_b(const int2* __restrict__ pairs,
                                                   const int* __restrict__ bcur,
                                                   int* __restrict__ cursor,
                                                   int* __restrict__ csr) {
  const int w = blockIdx.x & 7;
  const int slice = blockIdx.x >> 3;
  const int nsl = gridDim.x >> 3;
  const int cnt = bcur[w] - w * CAP;
  const long b0 = (long)w * CAP;
  const long lo = b0 + (long)slice * cnt / nsl;
  const long hi = b0 + (long)(slice + 1) * cnt / nsl;
  for (long i = lo + threadIdx.x; i < hi; i += 256) {
    int2 p = pairs[i];
    int pos = atomicAdd(&cursor[p.y], 1);
    csr[pos] = p.x;
  }
}

__global__ void k_dinv(const int* __restrict__ counts, float* __restrict__ dinv) {
  int i = blockIdx.x * 256 + threadIdx.x;
  if (i < NN) dinv[i] = rsqrtf((float)counts[i] + 1.0f);  // +1 self-loop
}

// ---- 3-kernel exclusive scan of counts[NN] -> rowptr ----------------------
__global__ __launch_bounds__(512) void k_scan1(const int* __restrict__ counts,
                                               int* __restrict__ rowptr,
                                               int* __restrict__ bsum) {
  __shared__ int sm[512];
  int tid = threadIdx.x;
  int i = blockIdx.x * 512 + tid;
  int v = (i < NN) ? counts[i] : 0;
  sm[tid] = v;
  __syncthreads();
  for (int off = 1; off < 512; off <<= 1) {
    int t = (tid >= off) ? sm[tid - off] : 0;
    __syncthreads();
    sm[tid] += t;
    __syncthreads();
  }
  if (i < NN) rowptr[i] = sm[tid] - v;
  if (tid == 511) bsum[blockIdx.x] = sm[tid];
}

__global__ void k_scan2(int* __restrict__ bsum, int nb) {
  if (threadIdx.x == 0 && blockIdx.x == 0) {
    int run = 0;
    for (int b = 0; b < nb; ++b) { int v = bsum[b]; bsum[b] = run; run += v; }
  }
}

__global__ __launch_bounds__(512) void k_scan3(int* __restrict__ rowptr,
                                               int* __restrict__ cursor,
                                               const int* __restrict__ bsum, int E) {
  int i = blockIdx.x * 512 + threadIdx.x;
  if (i < NN) {
    int v = rowptr[i] + bsum[blockIdx.x];
    rowptr[i] = v;
    cursor[i] = v;
  }
  if (i == 0) rowptr[NN] = E;
}

// ---------------------------------------------------------------------------
// W prep: Wt[n][k] fp16 from W[k][n] fp32 (tiny, once per call per layer).
// ---------------------------------------------------------------------------
template <int COUT>
__global__ void k_wprep(const float* __restrict__ W, f16* __restrict__ Wt) {
  int idx = blockIdx.x * 256 + threadIdx.x;
  if (idx < 128 * COUT) {
    int k = idx / COUT, n = idx % COUT;
    Wt[n * 128 + k] = (f16)W[idx];
  }
}

// ---------------------------------------------------------------------------
// MFMA GEMM: hn[row] = ((relu?)X[row] @ W) * dinv[row], fp16 out.
// Block: 256 thr / 4 waves, M-tile 128 (32 rows/wave), full K=128 staged.
// LDS XOR-swizzle (byte ^= (row&7)<<4) for conflict-free ds_read_b128.
// A-frag: lane holds A[l&15][k(g,j)]; B-frag: B[k(g,j)][l&15] — same k-map,
// so the HW's physical k-slot permutation cancels between A and B.
// ---------------------------------------------------------------------------
template <int COUT, bool RELU, typename TIN>
__global__ __launch_bounds__(256) void gemm_mfma(const TIN* __restrict__ X,
                                                 const f16* __restrict__ Wt,
                                                 const float* __restrict__ dinv,
                                                 f16* __restrict__ Y) {
  constexpr int NF = COUT / 16;
  __shared__ f16 Al[128 * 128];
  __shared__ f16 Bl[COUT * 128];
  const int tid = threadIdx.x;
  const long row0 = (long)blockIdx.x * 128;

  // stage W tile (COUT*16 chunks of 8 halves)
  for (int c = tid; c < COUT * 16; c += 256) {
    int n = c >> 4, g = c & 15;
    f16x8 v = *(const f16x8*)&Wt[n * 128 + g * 8];
    *(f16x8*)((char*)Bl + n * 256 + ((g * 16) ^ ((n & 7) << 4))) = v;
  }
  // stage X tile (2048 chunks of 8 elems), convert to fp16 (+relu)
  for (int c = tid; c < 2048; c += 256) {
    int r = c >> 4, g = c & 15;
    long grow = row0 + r;
    f16x8 v;
    if (grow < NN) {
      if constexpr (sizeof(TIN) == 4) {
        const float4* p = (const float4*)&X[grow * 128 + g * 8];
        float4 p0 = p[0], p1 = p[1];
        float f[8] = {p0.x, p0.y, p0.z, p0.w, p1.x, p1.y, p1.z, p1.w};
#pragma unroll
        for (int j = 0; j < 8; ++j) {
          float t = RELU ? fmaxf(f[j], 0.f) : f[j];
          v[j] = (f16)t;
        }
      } else {
        v = *(const f16x8*)&X[grow * 128 + g * 8];
        if (RELU) {
#pragma unroll
          for (int j = 0; j < 8; ++j) v[j] = v[j] > (f16)0 ? v[j] : (f16)0;
        }
      }
    } else {
#pragma unroll
      for (int j = 0; j < 8; ++j) v[j] = (f16)0;
    }
    *(f16x8*)((char*)Al + r * 256 + ((g * 16) ^ ((r & 7) << 4))) = v;
  }
  __syncthreads();

  const int l = tid & 63, w = tid >> 6;
  const int lm = l & 15, lg = l >> 4;
  const int r0 = w * 32 + lm, r1 = r0 + 16;

  f32x4 acc0[NF], acc1[NF];
#pragma unroll
  for (int nf = 0; nf < NF; ++nf) {
    acc0[nf] = (f32x4)(0.f);
    acc1[nf] = (f32x4)(0.f);
  }

#pragma unroll
  for (int kk = 0; kk < 4; ++kk) {
    const int kb = kk * 64 + lg * 16;
    f16x8 a0 = *(const f16x8*)((const char*)Al + r0 * 256 + (kb ^ ((r0 & 7) << 4)));
    f16x8 a1 = *(const f16x8*)((const char*)Al + r1 * 256 + (kb ^ ((r1 & 7) << 4)));
#pragma unroll
    for (int nf = 0; nf < NF; ++nf) {
      int n = nf * 16 + lm;
      f16x8 b = *(const f16x8*)((const char*)Bl + n * 256 + (kb ^ ((n & 7) << 4)));
      acc0[nf] = __builtin_amdgcn_mfma_f32_16x16x32_f16(a0, b, acc0[nf], 0, 0, 0);
      acc1[nf] = __builtin_amdgcn_mfma_f32_16x16x32_f16(a1, b, acc1[nf], 0, 0, 0);
    }
  }

  // epilogue: D row=(lg*4+reg), col=lm (m89-verified C/D layout), *dinv
#pragma unroll
  for (int reg = 0; reg < 4; ++reg) {
    long gr0 = row0 + w * 32 + lg * 4 + reg;
    long gr1 = gr0 + 16;
    float d0 = (gr0 < NN) ? dinv[gr0] : 0.f;
    float d1 = (gr1 < NN) ? dinv[gr1] : 0.f;
#pragma unroll
    for (int nf = 0; nf < NF; ++nf) {
      if (gr0 < NN) Y[gr0 * COUT + nf * 16 + lm] = (f16)(acc0[nf][reg] * d0);
      if (gr1 < NN) Y[gr1 * COUT + nf * 16 + lm] = (f16)(acc1[nf][reg] * d1);
    }
  }
}

// ---------------------------------------------------------------------------
// Gather: out[d] = dinv[d]*(hn[d] + sum_{s in N(d)} hn[s]) + bias.
// ---------------------------------------------------------------------------
template <int C, typename TOUT>
__global__ __launch_bounds__(256) void k_agg_csr(const __half* __restrict__ hn,
                                                 const int* __restrict__ rowptr,
                                                 const int* __restrict__ csr,
                                                 const float* __restrict__ dinv,
                                                 const float* __restrict__ bias,
                                                 TOUT* __restrict__ out) {
  constexpr int TP = C / 8;
  long t = (long)blockIdx.x * 256 + threadIdx.x;
  int d = (int)(t / TP);
  if (d >= NN) return;
  int c8 = (int)(t % TP) * 8;

  float acc[8];
  {
    float4 raw = *(const float4*)&hn[(long)d * C + c8];
    const __half2* h2 = (const __half2*)&raw;
#pragma unroll
    for (int q = 0; q < 4; ++q) {
      float2 f = __half22float2(h2[q]);
      acc[2 * q] = f.x; acc[2 * q + 1] = f.y;
    }
  }
  int e = rowptr[d];
  const int end = rowptr[d + 1];

  for (; e + 4 <= end; e += 4) {
    int s0 = csr[e], s1 = csr[e + 1], s2 = csr[e + 2], s3 = csr[e + 3];
    float4 r0 = *(const float4*)&hn[(long)s0 * C + c8];
    float4 r1 = *(const float4*)&hn[(long)s1 * C + c8];
    float4 r2 = *(const float4*)&hn[(long)s2 * C + c8];
    float4 r3 = *(const float4*)&hn[(long)s3 * C + c8];
    const __half2* a0 = (const __half2*)&r0;
    const __half2* a1 = (const __half2*)&r1;
    const __half2* a2 = (const __half2*)&r2;
    const __half2* a3 = (const __half2*)&r3;
#pragma unroll
    for (int q = 0; q < 4; ++q) {
      float2 f0 = __half22float2(a0[q]);
      float2 f1 = __half22float2(a1[q]);
      float2 f2 = __half22float2(a2[q]);
      float2 f3 = __half22float2(a3[q]);
      acc[2 * q]     += (f0.x + f1.x) + (f2.x + f3.x);
      acc[2 * q + 1] += (f0.y + f1.y) + (f2.y + f3.y);
    }
  }
  for (; e < end; ++e) {
    int s = csr[e];
    float4 r0 = *(const float4*)&hn[(long)s * C + c8];
    const __half2* a0 = (const __half2*)&r0;
#pragma unroll
    for (int q = 0; q < 4; ++q) {
      float2 f0 = __half22float2(a0[q]);
      acc[2 * q] += f0.x; acc[2 * q + 1] += f0.y;
    }
  }

  float dd = dinv[d];
  float4 b0 = *(const float4*)&bias[c8];
  float4 b1 = *(const float4*)&bias[c8 + 4];
  float o[8];
  o[0] = acc[0] * dd + b0.x; o[1] = acc[1] * dd + b0.y;
  o[2] = acc[2] * dd + b0.z; o[3] = acc[3] * dd + b0.w;
  o[4] = acc[4] * dd + b1.x; o[5] = acc[5] * dd + b1.y;
  o[6] = acc[6] * dd + b1.z; o[7] = acc[7] * dd + b1.w;

  if constexpr (sizeof(TOUT) == 2) {
    __half2 hp[4];
    hp[0] = __floats2half2_rn(o[0], o[1]);
    hp[1] = __floats2half2_rn(o[2], o[3]);
    hp[2] = __floats2half2_rn(o[4], o[5]);
    hp[3] = __floats2half2_rn(o[6], o[7]);
    *(float4*)&out[(long)d * C + c8] = *(float4*)hp;
  } else {
    *(float4*)&out[(long)d * C + c8]     = make_float4(o[0], o[1], o[2], o[3]);
    *(float4*)&out[(long)d * C + c8 + 4] = make_float4(o[4], o[5], o[6], o[7]);
  }
}

extern "C" void kernel_launch(void* const* d_in, const int* in_sizes, int n_in,
                              void* d_out, int out_size, void* d_ws, size_t ws_size,
                              hipStream_t stream) {
  const float* x  = (const float*)d_in[0];
  const void*  ep = d_in[1];
  const float* W1 = (const float*)d_in[2];
  const float* b1 = (const float*)d_in[3];
  const float* W2 = (const float*)d_in[4];
  const float* b2 = (const float*)d_in[5];
  float* out = (float*)d_out;
  const int E = in_sizes[1] / 2;

  // workspace layout (int-element offsets from base)
  float*  wsf    = (float*)d_ws;
  int*    wsi    = (int*)d_ws;
  int*    flag   = wsi;                        // [0]
  int*    bcur   = wsi + 16;                   // 8
  float*  dinv   = wsf + 64;                   // 100000 f
  int*    counts = wsi + 100096;               // 100000 (reused as cursor)
  int*    rowptr = wsi + 200128;               // 100001
  int*    bsum   = wsi + 300160;               // 256
  int*    csr    = wsi + 300416;               // 1600000
  int2*   pairs  = (int2*)(wsi + 1900416);     // 8*CAP int2
  f16*    Wt1    = (f16*)(wsi + 5177216);      // 16384 halves
  f16*    Wt2    = (f16*)(wsi + 5185408);      // 8192 halves
  f16*    hn1    = (f16*)(wsi + 5189504);      // 12.8M halves
  f16*    a1     = (f16*)(wsi + 11589504);     // 12.8M halves
  f16*    hn2    = hn1;                        // hn1 dead once a1 built
  int*    cursor = counts;

  const int NB = (NN + 511) / 512;             // 196
  const int ABLK = (E + 256 * EPB - 1) / (256 * EPB);
  const int GB = (NN + 127) / 128;             // 782

  k_detect<<<1, 1024, 0, stream>>>((const unsigned*)ep, flag);
  k_init8<<<1, 64, 0, stream>>>(bcur);
  k_zero<<<(NN + 255) / 256, 256, 0, stream>>>(counts, NN);
  k_wprep<128><<<64, 256, 0, stream>>>(W1, Wt1);
  k_wprep<64><<<32, 256, 0, stream>>>(W2, Wt2);
  k_bucket<<<ABLK, 256, 0, stream>>>(ep, flag, E, bcur, pairs);
  k_hist_b<<<2048, 256, 0, stream>>>(pairs, bcur, counts);
  k_dinv<<<(NN + 255) / 256, 256, 0, stream>>>(counts, dinv);
  k_scan1<<<NB, 512, 0, stream>>>(counts, rowptr, bsum);
  k_scan2<<<1, 64, 0, stream>>>(bsum, NB);
  k_scan3<<<NB, 512, 0, stream>>>(rowptr, cursor, bsum, E);
  k_scatter_b<<<2048, 256, 0, stream>>>(pairs, bcur, cursor, csr);

  // layer 1
  gemm_mfma<128, false, float><<<GB, 256, 0, stream>>>(x, Wt1, dinv, hn1);
  k_agg_csr<128, __half><<<(NN * 16) / 256, 256, 0, stream>>>(
      (const __half*)hn1, rowptr, csr, dinv, b1, (__half*)a1);

  // layer 2 (relu fused into staging conversion)
  gemm_mfma<64, true, f16><<<GB, 256, 0, stream>>>(a1, Wt2, dinv, hn2);
  k_agg_csr<64, float><<<(NN * 8) / 256, 256, 0, stream>>>(
      (const __half*)hn2, rowptr, csr, dinv, b2, out);
}